// Round 1
// baseline (418.223 us; speedup 1.0000x reference)
//
#include <hip/hip_runtime.h>
#include <math.h>

typedef _Float16 f16x8 __attribute__((ext_vector_type(8)));
typedef _Float16 f16x4 __attribute__((ext_vector_type(4)));
typedef float f32x4 __attribute__((ext_vector_type(4)));

__device__ __forceinline__ void async_copy16(const void* g, void* l) {
    __builtin_amdgcn_global_load_lds(
        (const __attribute__((address_space(1))) void*)g,
        (__attribute__((address_space(3))) void*)l, 16, 0, 0);
}

// ---------------- cast x (fp32) -> f16 ----------------
__global__ __launch_bounds__(256) void cast_f32_f16_kernel(
    const float4* __restrict__ in, f16x4* __restrict__ out) {
    int i = blockIdx.x * 256 + threadIdx.x;
    float4 v = in[i];
    f16x4 o;
    o[0] = (_Float16)v.x; o[1] = (_Float16)v.y;
    o[2] = (_Float16)v.z; o[3] = (_Float16)v.w;
    out[i] = o;
}

// ---------------- core pre-contractions ----------------
// E0[r][j][p][k][q] = sum_s c0b[r,j,p,s] * c0c[s,k,q]   (r8,j16,p16,k8,q16)
__global__ __launch_bounds__(256) void build_E0_kernel(
    const float* __restrict__ c0b, const float* __restrict__ c0c, float* __restrict__ E0) {
    int idx = blockIdx.x * 256 + threadIdx.x;  // 262144
    int q = idx & 15, k = (idx >> 4) & 7, p = (idx >> 7) & 15, j = (idx >> 11) & 15, r = idx >> 15;
    float s = 0.f;
#pragma unroll
    for (int ss = 0; ss < 8; ++ss)
        s += c0b[((r * 16 + j) * 16 + p) * 8 + ss] * c0c[(ss * 8 + k) * 16 + q];
    E0[idx] = s;
}

// W0t[n][kin] f16, n=(o*16+p)*16+q (4096), kin=(i*16+j)*8+k (1024)
__global__ __launch_bounds__(256) void build_W0t_kernel(
    const float* __restrict__ c0a, const float* __restrict__ E0, _Float16* __restrict__ W0t) {
    int idx = blockIdx.x * 256 + threadIdx.x;  // 4096*1024
    int kin = idx & 1023, n = idx >> 10;
    int i = kin >> 7, j = (kin >> 3) & 15, k = kin & 7;
    int q = n & 15, p = (n >> 4) & 15, o = n >> 8;
    float s = 0.f;
#pragma unroll
    for (int r = 0; r < 8; ++r)
        s += c0a[(i * 16 + o) * 8 + r] * E0[(((r * 16 + j) * 16 + p) * 8 + k) * 16 + q];
    W0t[idx] = (_Float16)s;
}

// E1[r][j][p][k][q] = sum_s c1b[r,j,p,s] * c1c[s,k,q]   (r8,j16,p16,k16,q8)
__global__ __launch_bounds__(256) void build_E1_kernel(
    const float* __restrict__ c1b, const float* __restrict__ c1c, float* __restrict__ E1) {
    int idx = blockIdx.x * 256 + threadIdx.x;  // 262144
    int q = idx & 7, k = (idx >> 3) & 15, p = (idx >> 7) & 15, j = (idx >> 11) & 15, r = idx >> 15;
    float s = 0.f;
#pragma unroll
    for (int ss = 0; ss < 8; ++ss)
        s += c1b[((r * 16 + j) * 16 + p) * 8 + ss] * c1c[(ss * 16 + k) * 8 + q];
    E1[idx] = s;
}

// W1t[n][kin] f16, n=(o*16+p)*8+q (1024), kin=(i*16+j)*16+k (4096)
__global__ __launch_bounds__(256) void build_W1t_kernel(
    const float* __restrict__ c1a, const float* __restrict__ E1, _Float16* __restrict__ W1t) {
    int idx = blockIdx.x * 256 + threadIdx.x;  // 1024*4096
    int kin = idx & 4095, n = idx >> 12;
    int i = kin >> 8, j = (kin >> 4) & 15, k = kin & 15;
    int q = n & 7, p = (n >> 3) & 15, o = n >> 7;
    float s = 0.f;
#pragma unroll
    for (int r = 0; r < 8; ++r)
        s += c1a[(i * 8 + o) * 8 + r] * E1[(((r * 16 + j) * 16 + p) * 16 + k) * 8 + q];
    W1t[idx] = (_Float16)s;
}

// ---------------- GEMM: C = A(MxK) * Bt(NxK)^T, m97-style ----------------
// OUTMODE 0: fp32 out = acc + bias
// OUTMODE 1: f16 out = gelu(acc + bias)
template <int OUTMODE>
__global__ __launch_bounds__(256) void gemm_bt_kernel(
    const _Float16* __restrict__ A, const _Float16* __restrict__ Bt,
    const float* __restrict__ bias, void* __restrict__ Cout,
    int M, int N, int K) {
    constexpr int BK = 32;
    __shared__ alignas(16) _Float16 sA[128 * BK];
    __shared__ alignas(16) _Float16 sB[128 * BK];

    const int t = threadIdx.x;
    const int lane = t & 63;
    const int w = t >> 6;
    const int m0 = blockIdx.x * 128;
    const int n0 = blockIdx.y * 128;
    const int wm = (w & 1) * 64;
    const int wn = (w >> 1) * 64;
    const int lm = lane & 15;
    const int lq = lane >> 4;

    f32x4 acc[4][4] = {};

    const int srow = t >> 2;        // 0..63
    const int sk = (t & 3) * 8;     // k element offset
    const _Float16* gA = A + (size_t)(m0 + srow) * K + sk;
    const _Float16* gB = Bt + (size_t)(n0 + srow) * K + sk;
    _Float16* lA = sA + srow * BK + sk;   // == byte offset t*16 (wave base + lane*16)
    _Float16* lB = sB + srow * BK + sk;
    const size_t rowskip = (size_t)64 * K;

    for (int k0 = 0; k0 < K; k0 += BK) {
        async_copy16(gA + k0, lA);
        async_copy16(gA + k0 + rowskip, lA + 64 * BK);
        async_copy16(gB + k0, lB);
        async_copy16(gB + k0 + rowskip, lB + 64 * BK);
        __syncthreads();

        f16x8 af[4], bf[4];
#pragma unroll
        for (int i = 0; i < 4; ++i) {
            af[i] = *(const f16x8*)(sA + (wm + i * 16 + lm) * BK + lq * 8);
            bf[i] = *(const f16x8*)(sB + (wn + i * 16 + lm) * BK + lq * 8);
        }
#pragma unroll
        for (int i = 0; i < 4; ++i)
#pragma unroll
            for (int j = 0; j < 4; ++j)
                acc[i][j] = __builtin_amdgcn_mfma_f32_16x16x32_f16(af[i], bf[j], acc[i][j], 0, 0, 0);
        __syncthreads();
    }

    if (OUTMODE == 1) {
        _Float16* C = (_Float16*)Cout;
#pragma unroll
        for (int i = 0; i < 4; ++i)
#pragma unroll
            for (int j = 0; j < 4; ++j) {
                int col = n0 + wn + j * 16 + lm;
                float bv = bias[col];
#pragma unroll
                for (int r = 0; r < 4; ++r) {
                    int row = m0 + wm + i * 16 + lq * 4 + r;
                    float v = acc[i][j][r] + bv;
                    v = 0.5f * v * (1.0f + erff(v * 0.70710678118654752f));
                    C[(size_t)row * N + col] = (_Float16)v;
                }
            }
    } else {
        float* C = (float*)Cout;
#pragma unroll
        for (int i = 0; i < 4; ++i)
#pragma unroll
            for (int j = 0; j < 4; ++j) {
                int col = n0 + wn + j * 16 + lm;
                float bv = bias[col];
#pragma unroll
                for (int r = 0; r < 4; ++r) {
                    int row = m0 + wm + i * 16 + lq * 4 + r;
                    C[(size_t)row * N + col] = acc[i][j][r] + bv;
                }
            }
    }
}

extern "C" void kernel_launch(void* const* d_in, const int* in_sizes, int n_in,
                              void* d_out, int out_size, void* d_ws, size_t ws_size,
                              hipStream_t stream) {
    const float* x   = (const float*)d_in[0];
    const float* c0a = (const float*)d_in[1];
    const float* c0b = (const float*)d_in[2];
    const float* c0c = (const float*)d_in[3];
    const float* b0  = (const float*)d_in[4];
    const float* c1a = (const float*)d_in[5];
    const float* c1b = (const float*)d_in[6];
    const float* c1c = (const float*)d_in[7];
    const float* b1  = (const float*)d_in[8];
    float* out = (float*)d_out;

    char* ws = (char*)d_ws;
    _Float16* xh  = (_Float16*)(ws);                          // 16 MB
    _Float16* W0t = (_Float16*)(ws + (size_t)(16u << 20));    //  8 MB
    _Float16* W1t = (_Float16*)(ws + (size_t)(24u << 20));    //  8 MB
    _Float16* h   = (_Float16*)(ws + (size_t)(32u << 20));    // 64 MB (8192x4096 f16)
    float* E0     = (float*)(ws + (size_t)(32u << 20));       //  1 MB, overlaps h (consumed first)
    float* E1     = (float*)(ws + (size_t)(33u << 20));       //  1 MB, overlaps h (consumed first)

    // 1) cast x -> f16   (8192*1024 / 4 = 2097152 float4s)
    cast_f32_f16_kernel<<<dim3(8192), dim3(256), 0, stream>>>((const float4*)x, (f16x4*)xh);
    // 2) pre-contract TT cores into dense transposed weights (N x K, f16)
    build_E0_kernel<<<dim3(1024), dim3(256), 0, stream>>>(c0b, c0c, E0);
    build_E1_kernel<<<dim3(1024), dim3(256), 0, stream>>>(c1b, c1c, E1);
    build_W0t_kernel<<<dim3(16384), dim3(256), 0, stream>>>(c0a, E0, W0t);
    build_W1t_kernel<<<dim3(16384), dim3(256), 0, stream>>>(c1a, E1, W1t);
    // 3) h = gelu(x @ W0 + b0)   M=8192 N=4096 K=1024
    gemm_bt_kernel<1><<<dim3(64, 32), dim3(256), 0, stream>>>(xh, W0t, b0, (void*)h, 8192, 4096, 1024);
    // 4) out = h @ W1 + b1       M=8192 N=1024 K=4096
    gemm_bt_kernel<0><<<dim3(64, 8), dim3(256), 0, stream>>>(h, W1t, b1, (void*)out, 8192, 1024, 4096);
}

// Round 2
// 309.244 us; speedup vs baseline: 1.3524x; 1.3524x over previous
//
#include <hip/hip_runtime.h>
#include <math.h>

typedef _Float16 f16x8 __attribute__((ext_vector_type(8)));
typedef _Float16 f16x4 __attribute__((ext_vector_type(4)));
typedef float f32x4 __attribute__((ext_vector_type(4)));

__device__ __forceinline__ void async_copy16(const void* g, void* l) {
    __builtin_amdgcn_global_load_lds(
        (const __attribute__((address_space(1))) void*)g,
        (__attribute__((address_space(3))) void*)l, 16, 0, 0);
}

// ---------------- cast x (fp32) -> f16 ----------------
__global__ __launch_bounds__(256) void cast_f32_f16_kernel(
    const float4* __restrict__ in, f16x4* __restrict__ out) {
    int i = blockIdx.x * 256 + threadIdx.x;
    float4 v = in[i];
    f16x4 o;
    o[0] = (_Float16)v.x; o[1] = (_Float16)v.y;
    o[2] = (_Float16)v.z; o[3] = (_Float16)v.w;
    out[i] = o;
}

// ---------------- core pre-contractions ----------------
// E0[r][j][p][k][q] = sum_s c0b[r,j,p,s] * c0c[s,k,q]   (r8,j16,p16,k8,q16)
__global__ __launch_bounds__(256) void build_E0_kernel(
    const float* __restrict__ c0b, const float* __restrict__ c0c, float* __restrict__ E0) {
    int idx = blockIdx.x * 256 + threadIdx.x;  // 262144
    int q = idx & 15, k = (idx >> 4) & 7, p = (idx >> 7) & 15, j = (idx >> 11) & 15, r = idx >> 15;
    float s = 0.f;
#pragma unroll
    for (int ss = 0; ss < 8; ++ss)
        s += c0b[((r * 16 + j) * 16 + p) * 8 + ss] * c0c[(ss * 8 + k) * 16 + q];
    E0[idx] = s;
}

// E1[r][j][p][k][q] = sum_s c1b[r,j,p,s] * c1c[s,k,q]   (r8,j16,p16,k16,q8)
__global__ __launch_bounds__(256) void build_E1_kernel(
    const float* __restrict__ c1b, const float* __restrict__ c1c, float* __restrict__ E1) {
    int idx = blockIdx.x * 256 + threadIdx.x;  // 262144
    int q = idx & 7, k = (idx >> 3) & 15, p = (idx >> 7) & 15, j = (idx >> 11) & 15, r = idx >> 15;
    float s = 0.f;
#pragma unroll
    for (int ss = 0; ss < 8; ++ss)
        s += c1b[((r * 16 + j) * 16 + p) * 8 + ss] * c1c[(ss * 16 + k) * 8 + q];
    E1[idx] = s;
}

// W0t[n][kin] f16, n=(o*16+p)*16+q (4096), kin=(i*16+j)*8+k (1024)
// lanes = (q,k) -> coalesced E0 reads; E0[r] in regs reused over (i,o)
__global__ __launch_bounds__(256) void build_W0t_v2(
    const float* __restrict__ c0a, const float* __restrict__ E0, _Float16* __restrict__ W0t) {
    const int j = blockIdx.x >> 4, p = blockIdx.x & 15;
    const int t = threadIdx.x;
    const int q = t & 15, k = (t >> 4) & 7, ih = t >> 7;
    float e[8];
#pragma unroll
    for (int r = 0; r < 8; ++r)
        e[r] = E0[(((r * 16 + j) * 16 + p) * 8 + k) * 16 + q];
#pragma unroll
    for (int ii = 0; ii < 4; ++ii) {
        const int i = ih * 4 + ii;
#pragma unroll
        for (int o = 0; o < 16; ++o) {
            float s = 0.f;
#pragma unroll
            for (int r = 0; r < 8; ++r) s += c0a[(i * 16 + o) * 8 + r] * e[r];
            W0t[(size_t)((o * 16 + p) * 16 + q) * 1024 + (i * 128 + j * 8 + k)] = (_Float16)s;
        }
    }
}

// W1t[n][kin] f16, n=(o*16+p)*8+q (1024), kin=(i*16+j)*16+k (4096)
__global__ __launch_bounds__(256) void build_W1t_v2(
    const float* __restrict__ c1a, const float* __restrict__ E1, _Float16* __restrict__ W1t) {
    const int j = blockIdx.x >> 4, p = blockIdx.x & 15;
    const int t = threadIdx.x;
    const int q = t & 7, k = (t >> 3) & 15, ih = t >> 7;
    float e[8];
#pragma unroll
    for (int r = 0; r < 8; ++r)
        e[r] = E1[(((r * 16 + j) * 16 + p) * 16 + k) * 8 + q];
#pragma unroll
    for (int ii = 0; ii < 8; ++ii) {
        const int i = ih * 8 + ii;
#pragma unroll
        for (int o = 0; o < 8; ++o) {
            float s = 0.f;
#pragma unroll
            for (int r = 0; r < 8; ++r) s += c1a[(i * 8 + o) * 8 + r] * e[r];
            W1t[(size_t)((o * 16 + p) * 8 + q) * 4096 + (i * 16 + j) * 16 + k] = (_Float16)s;
        }
    }
}

// ---------------- GEMM: C = A(MxK) * Bt(NxK)^T ----------------
// XOR-swizzled LDS layout: within each wave's 16-row / 1KB staging window,
// chunk slot s of row rho holds k-chunk (s ^ ((rho>>1)&3)). Staging stays
// contiguous lane*16 (global_load_lds constraint); reads hit all 8 bank quads.
// OUTMODE 0: fp32 out = acc + bias
// OUTMODE 1: f16 out = fast_gelu(acc + bias)
template <int OUTMODE>
__global__ __launch_bounds__(256) void gemm_bt_kernel(
    const _Float16* __restrict__ A, const _Float16* __restrict__ Bt,
    const float* __restrict__ bias, void* __restrict__ Cout,
    int M, int N, int K) {
    constexpr int BK = 32;
    __shared__ alignas(16) _Float16 sA[128 * BK];
    __shared__ alignas(16) _Float16 sB[128 * BK];

    const int t = threadIdx.x;
    const int lane = t & 63;
    const int w = t >> 6;
    const int m0 = blockIdx.x * 128;
    const int n0 = blockIdx.y * 128;
    const int wm = (w & 1) * 64;
    const int wn = (w >> 1) * 64;
    const int lm = lane & 15;
    const int lq = lane >> 4;
    const int kxor = lq ^ ((lm >> 1) & 3);  // de-swizzle for fragment reads

    f32x4 acc[4][4] = {};

    const int srow = t >> 2;                          // 0..63
    const int sk = ((t & 3) ^ ((t >> 3) & 3)) * 8;    // swizzled k-chunk to fetch
    const _Float16* gA = A + (size_t)(m0 + srow) * K + sk;
    const _Float16* gB = Bt + (size_t)(n0 + srow) * K + sk;
    _Float16* lA = sA + srow * BK + (t & 3) * 8;  // dst = wave base + lane*16 (contiguous)
    _Float16* lB = sB + srow * BK + (t & 3) * 8;
    const size_t rowskip = (size_t)64 * K;

    for (int k0 = 0; k0 < K; k0 += BK) {
        async_copy16(gA + k0, lA);
        async_copy16(gA + k0 + rowskip, lA + 64 * BK);
        async_copy16(gB + k0, lB);
        async_copy16(gB + k0 + rowskip, lB + 64 * BK);
        __syncthreads();

        f16x8 af[4], bf[4];
#pragma unroll
        for (int i = 0; i < 4; ++i) {
            af[i] = *(const f16x8*)(sA + (wm + i * 16 + lm) * BK + kxor * 8);
            bf[i] = *(const f16x8*)(sB + (wn + i * 16 + lm) * BK + kxor * 8);
        }
#pragma unroll
        for (int i = 0; i < 4; ++i)
#pragma unroll
            for (int j = 0; j < 4; ++j)
                acc[i][j] = __builtin_amdgcn_mfma_f32_16x16x32_f16(af[i], bf[j], acc[i][j], 0, 0, 0);
        __syncthreads();
    }

    if (OUTMODE == 1) {
        _Float16* C = (_Float16*)Cout;
#pragma unroll
        for (int i = 0; i < 4; ++i)
#pragma unroll
            for (int j = 0; j < 4; ++j) {
                int col = n0 + wn + j * 16 + lm;
                float bv = bias[col];
#pragma unroll
                for (int r = 0; r < 4; ++r) {
                    int row = m0 + wm + i * 16 + lq * 4 + r;
                    float v = acc[i][j][r] + bv;
                    // tanh-form GELU via exp2+rcp (max dev from erf form ~3e-4)
                    float u = v * (0.7978845608028654f + 0.0356774081363001f * v * v);
                    float e = __builtin_amdgcn_exp2f(u * 2.8853900817779268f);  // exp(2u)
                    float rc = __builtin_amdgcn_rcpf(e + 1.0f);
                    C[(size_t)row * N + col] = (_Float16)(v * (1.0f - rc));
                }
            }
    } else {
        float* C = (float*)Cout;
#pragma unroll
        for (int i = 0; i < 4; ++i)
#pragma unroll
            for (int j = 0; j < 4; ++j) {
                int col = n0 + wn + j * 16 + lm;
                float bv = bias[col];
#pragma unroll
                for (int r = 0; r < 4; ++r) {
                    int row = m0 + wm + i * 16 + lq * 4 + r;
                    C[(size_t)row * N + col] = acc[i][j][r] + bv;
                }
            }
    }
}

extern "C" void kernel_launch(void* const* d_in, const int* in_sizes, int n_in,
                              void* d_out, int out_size, void* d_ws, size_t ws_size,
                              hipStream_t stream) {
    const float* x   = (const float*)d_in[0];
    const float* c0a = (const float*)d_in[1];
    const float* c0b = (const float*)d_in[2];
    const float* c0c = (const float*)d_in[3];
    const float* b0  = (const float*)d_in[4];
    const float* c1a = (const float*)d_in[5];
    const float* c1b = (const float*)d_in[6];
    const float* c1c = (const float*)d_in[7];
    const float* b1  = (const float*)d_in[8];
    float* out = (float*)d_out;

    char* ws = (char*)d_ws;
    _Float16* xh  = (_Float16*)(ws);                          // 16 MB
    _Float16* W0t = (_Float16*)(ws + (size_t)(16u << 20));    //  8 MB
    _Float16* W1t = (_Float16*)(ws + (size_t)(24u << 20));    //  8 MB
    _Float16* h   = (_Float16*)(ws + (size_t)(32u << 20));    // 64 MB (8192x4096 f16)
    float* E0     = (float*)(ws + (size_t)(32u << 20));       //  1 MB, overlaps h (consumed first)
    float* E1     = (float*)(ws + (size_t)(33u << 20));       //  1 MB, overlaps h (consumed first)

    // 1) cast x -> f16
    cast_f32_f16_kernel<<<dim3(8192), dim3(256), 0, stream>>>((const float4*)x, (f16x4*)xh);
    // 2) pre-contract TT cores into dense transposed weights (N x K, f16)
    build_E0_kernel<<<dim3(1024), dim3(256), 0, stream>>>(c0b, c0c, E0);
    build_E1_kernel<<<dim3(1024), dim3(256), 0, stream>>>(c1b, c1c, E1);
    build_W0t_v2<<<dim3(256), dim3(256), 0, stream>>>(c0a, E0, W0t);
    build_W1t_v2<<<dim3(256), dim3(256), 0, stream>>>(c1a, E1, W1t);
    // 3) h = gelu(x @ W0 + b0)   M=8192 N=4096 K=1024
    gemm_bt_kernel<1><<<dim3(64, 32), dim3(256), 0, stream>>>(xh, W0t, b0, (void*)h, 8192, 4096, 1024);
    // 4) out = h @ W1 + b1       M=8192 N=1024 K=4096
    gemm_bt_kernel<0><<<dim3(64, 8), dim3(256), 0, stream>>>(h, W1t, b1, (void*)out, 8192, 1024, 4096);
}